// Round 8
// baseline (173.976 us; speedup 1.0000x reference)
//
#include <hip/hip_runtime.h>

using frag_t = __attribute__((ext_vector_type(8))) short;   // 8 x bf16 (4 VGPRs)
using f32x4  = __attribute__((ext_vector_type(4))) float;   // MFMA C/D

#define L2E 1.4426950408889634f

#if __has_builtin(__builtin_amdgcn_exp2f)
#define EXP2(x) __builtin_amdgcn_exp2f(x)   // raw v_exp_f32 (no denormal fixup seq)
#else
#define EXP2(x) exp2f(x)
#endif

constexpr int B_  = 2, S_ = 2048, D_ = 1024, H_ = 16, HD_ = 64;
constexpr float QSCALE = 0.125f * L2E;   // fold softmax log2e into Q

__device__ __forceinline__ ushort f2bf(float f) {
  union { float f; unsigned u; } v; v.f = f;
  unsigned u = v.u;
  unsigned r = (u + 0x7FFFu + ((u >> 16) & 1u)) >> 16;  // round-nearest-even
  return (ushort)r;
}

// async 16B/lane global->LDS (lds dest = wave-uniform base + lane*16) [m97]
__device__ __forceinline__ void gld_lds16(const ushort* g, ushort* l) {
  __builtin_amdgcn_global_load_lds((const __attribute__((address_space(1))) void*)g,
                                   (__attribute__((address_space(3))) void*)l, 16, 0, 0);
}

// ---------- fused prep: x->bf16  |  Wqkv^T->bf16  |  Wproj^T->bf16 ----------
__global__ __launch_bounds__(256) void k_prep(
    const float* __restrict__ x, const float* __restrict__ Wqkv,
    const float* __restrict__ Wproj,
    ushort* __restrict__ Xbf, ushort* __restrict__ Wqt, ushort* __restrict__ Wpt) {
  int blk = blockIdx.x, tid = threadIdx.x;
  if (blk < 1024) {                                 // x convert: 4096 elems/block
    size_t base = (size_t)blk * 4096 + tid * 4;
    #pragma unroll
    for (int i = 0; i < 4; ++i) {
      float4 f = *(const float4*)(x + base + i * 1024);
      ushort4 o;
      o.x = f2bf(f.x); o.y = f2bf(f.y); o.z = f2bf(f.z); o.w = f2bf(f.w);
      *(ushort4*)(Xbf + base + i * 1024) = o;
    }
  } else {                                          // W [K,N] -> W^T [N,K] bf16, 64x64 tile
    __shared__ float tile[64][65];
    const float* in; ushort* out; int N, K, bx, by;
    if (blk < 1024 + 768) { int b2 = blk - 1024; in = Wqkv;  out = Wqt; N = 3072; K = 1024; bx = b2 % 48; by = b2 / 48; }
    else                  { int b2 = blk - 1792; in = Wproj; out = Wpt; N = 1024; K = 1024; bx = b2 % 16; by = b2 / 16; }
    int n0 = bx * 64, k0 = by * 64;
    int tx = tid & 63, ty = tid >> 6;               // (64,4)
    #pragma unroll
    for (int i = 0; i < 16; ++i)
      tile[ty + i * 4][tx] = in[(size_t)(k0 + ty + i * 4) * N + n0 + tx];
    __syncthreads();
    #pragma unroll
    for (int i = 0; i < 16; ++i)
      out[(size_t)(n0 + ty + i * 4) * K + k0 + tx] = f2bf(tile[tx][ty + i * 4]);
  }
}

// ---------- 128x384 8-phase QKV GEMM (R6 geometry, sigma V^T — validated) ----------
__global__ __launch_bounds__(512, 2) void k_gemm8(
    const ushort* __restrict__ A, const ushort* __restrict__ Bt,
    const float* __restrict__ bias,
    ushort* __restrict__ Qo, ushort* __restrict__ Ko, ushort* __restrict__ Vo) {
  __shared__ ushort smem[65536];                    // 128 KiB
  int tid = threadIdx.x;
  int lane = tid & 63, wave = tid >> 6;
  int quad = lane >> 4, li = lane & 15;
  int wm = wave >> 1, wn = wave & 1;                // 4M x 2N
  int wg = blockIdx.x;                              // 256 = 8(N) x 32(M)
  int bx = wg & 7, by = wg >> 3;                    // bx == XCD: B-panel L2-resident
  int m0 = by * 128, n0 = bx * 384;
  const ushort* Asrc = A  + (size_t)m0 * 1024;
  const ushort* Bsrc = Bt + (size_t)n0 * 1024;
  int schunk = (tid & 3) ^ ((tid >> 4) & 3);        // stored pos -> source chunk
  int pos    = (quad ^ ((li >> 2) & 3)) * 8;        // frag read position (elems)

#define STGA(BI, KS, KT) \
    gld_lds16(&Asrc[(size_t)(tid >> 2) * 1024 + (KT)*64 + (KS)*32 + schunk*8], \
              &smem[(BI)*32768 + (KS)*4096 + wave*512])

#define STGB(BI, KS, KT) do { \
    _Pragma("unroll") \
    for (int p = 0; p < 3; ++p) \
      gld_lds16(&Bsrc[(size_t)(p*128 + (tid >> 2)) * 1024 + (KT)*64 + (KS)*32 + schunk*8], \
                &smem[(BI)*32768 + 8192 + (KS)*12288 + p*4096 + wave*512]); \
  } while (0)

  f32x4 acc[2][12] = {};
  frag_t af[2], bf[6];

#define PH(BI, KS, NH, STGS, W4) do { \
    if ((NH) == 0) { \
      _Pragma("unroll") \
      for (int mi = 0; mi < 2; ++mi) \
        af[mi] = *(const frag_t*)&smem[(BI)*32768 + (KS)*4096 + (wm*32 + mi*16 + li)*32 + pos]; \
    } \
    _Pragma("unroll") \
    for (int nj = 0; nj < 6; ++nj) \
      bf[nj] = *(const frag_t*)&smem[(BI)*32768 + 8192 + (KS)*12288 + (wn*192 + ((NH)*6 + nj)*16 + li)*32 + pos]; \
    STGS; \
    if (W4) asm volatile("s_waitcnt vmcnt(4)" ::: "memory"); \
    asm volatile("s_barrier" ::: "memory"); \
    __builtin_amdgcn_s_setprio(1); \
    _Pragma("unroll") \
    for (int mi = 0; mi < 2; ++mi) \
      _Pragma("unroll") \
      for (int nj = 0; nj < 6; ++nj) \
        acc[mi][(NH)*6 + nj] = __builtin_amdgcn_mfma_f32_16x16x32_bf16(af[mi], bf[nj], acc[mi][(NH)*6 + nj], 0, 0, 0); \
    __builtin_amdgcn_s_setprio(0); \
    asm volatile("s_barrier" ::: "memory"); \
  } while (0)

  STGA(0,0,0); STGB(0,0,0); STGA(0,1,0); STGB(0,1,0);
  STGA(1,0,1); STGB(1,0,1);
  asm volatile("s_waitcnt vmcnt(4)" ::: "memory");
  asm volatile("s_barrier" ::: "memory");

  for (int it = 0; it < 8; ++it) {                  // 2 K-tiles / iter, NT=16
    int t1 = 2*it + 1;
    int t2 = (2*it + 2 < 16) ? 2*it + 2 : 15;       // clamp: dead stage keeps
    int t3 = (2*it + 3 < 16) ? 2*it + 3 : 15;       //   vmcnt counts uniform
    PH(0,0,0, STGA(1,1,t1), 0);
    PH(0,0,1, STGB(1,1,t1), 0);
    PH(0,1,0, STGA(0,0,t2), 0);
    PH(0,1,1, STGB(0,0,t2), 1);
    PH(1,0,0, STGA(0,1,t2), 0);
    PH(1,0,1, STGB(0,1,t2), 0);
    PH(1,1,0, STGA(1,0,t3), 0);
    PH(1,1,1, STGB(1,0,t3), 1);
  }
#undef PH
#undef STGA
#undef STGB

  asm volatile("s_waitcnt vmcnt(0)" ::: "memory");  // drain dead stages before LDS reuse
  __syncthreads();

  // epilogue: C row = quad*4+r (M), col = li (N)  [m89/m91]
  #pragma unroll
  for (int nf = 0; nf < 12; ++nf) {
    int col0 = n0 + wn * 192 + nf * 16;             // 16-aligned, region-uniform
    int which = col0 >> 10;                         // 0=Q 1=K 2=V
    float bv = bias[col0 + li];
    if (which < 2) {                                // Q / K: [bh][s][hd]
      int d = (col0 + li) & 1023;
      int h = d >> 6, hd = d & 63;
      #pragma unroll
      for (int mi = 0; mi < 2; ++mi)
        #pragma unroll
        for (int r = 0; r < 4; ++r) {
          int grow = m0 + wm * 32 + mi * 16 + quad * 4 + r;
          int b = grow >> 11, s = grow & 2047;
          size_t off = (((size_t)b * H_ + h) * S_ + s) * HD_ + hd;
          float v = acc[mi][nf][r] + bv;
          if (which == 0) Qo[off] = f2bf(v * QSCALE);
          else            Ko[off] = f2bf(v);
        }
    } else {                                        // V -> sigma-permuted V^T (R6-validated)
      // natural key n = mi*16 + quad*4 + r (wave 32-span); position p = sigma(n):
      // within each 32-block, swap 4-groups 1<->2 of each 16 (involution),
      // matching attn's permlane32_swap frag basis.
      ushort* vl = &smem[wave * 640];               // [16 hd][40 pad] per wave
      int gq = (quad == 1 || quad == 2) ? (quad ^ 3) : quad;
      #pragma unroll
      for (int mi = 0; mi < 2; ++mi) {
        union { ushort u[4]; uint2 w; } pk;
        #pragma unroll
        for (int r = 0; r < 4; ++r) pk.u[r] = f2bf(acc[mi][nf][r] + bv);
        *(uint2*)&vl[li * 40 + mi * 16 + gq * 4] = pk.w;
      }
      int h = (col0 >> 6) & 15, hd0 = col0 & 63;
      int b = m0 >> 11, s0 = (m0 & 2047) + wm * 32;
      int rt = lane >> 2, kc = (lane & 3) * 8;      // 16 hd-rows x 4 key-chunks
      uint4 w = *(const uint4*)&vl[rt * 40 + kc];
      *(uint4*)&Vo[((size_t)(b * H_ + h) * HD_ + hd0 + rt) * S_ + s0 + kc] = w;
    }
  }
}

// ---------- proj GEMM: m97 128x128 (validated 912 TF ladder config) ----------
// R8: grid 8x32 = 256 WGs = 100% CU coverage; 32 MFMA/K-step (2x R6's
// MFMA:barrier ratio) vs 1 WG/CU (no inter-WG overlap). Isolated change.
__global__ __launch_bounds__(256) void k_proj(
    const ushort* __restrict__ A, const ushort* __restrict__ Bt,
    const float* __restrict__ bias, float* __restrict__ Co) {
  constexpr int BM = 128, BN = 128, BK = 64, MI = 4, NI = 4;
  constexpr int N = 1024, K = 1024;
  __shared__ ushort smem[(BM + BN) * BK];
  ushort* As = smem;
  ushort* Bs = smem + BM * BK;
  int tid  = threadIdx.x;
  int lane = tid & 63, wave = tid >> 6;
  int quad = lane >> 4, li = lane & 15;
  int mbase = (wave >> 1) * 64;                     // 2x2 waves, 64x64 each
  int nbase = (wave & 1) * 64;
  int m0 = blockIdx.y * BM, n0 = blockIdx.x * BN;
  int srow = lane >> 3;                             // within a wave: 8 rows x 128B
  int scol = ((lane & 7) ^ srow) * 8;               // XOR-swizzled global chunk
  f32x4 acc[MI][NI] = {};
  for (int k0 = 0; k0 < K; k0 += BK) {
    #pragma unroll
    for (int i = 0; i < 4; ++i) {                   // A: 128 rows
      int rbase = i * 32 + wave * 8;
      gld_lds16(&A[(size_t)(m0 + rbase + srow) * K + k0 + scol], &As[rbase * BK]);
    }
    #pragma unroll
    for (int i = 0; i < 4; ++i) {                   // B: 128 rows
      int rbase = i * 32 + wave * 8;
      gld_lds16(&Bt[(size_t)(n0 + rbase + srow) * K + k0 + scol], &Bs[rbase * BK]);
    }
    __syncthreads();                                // drains vmcnt (compiler-emitted)
    #pragma unroll
    for (int ks = 0; ks < 2; ++ks) {
      frag_t af[MI], bf[NI];
      #pragma unroll
      for (int mi = 0; mi < MI; ++mi)
        af[mi] = *(const frag_t*)&As[(mbase + mi * 16 + li) * BK + (((ks * 4 + quad) ^ (li & 7)) * 8)];
      #pragma unroll
      for (int ni = 0; ni < NI; ++ni)
        bf[ni] = *(const frag_t*)&Bs[(nbase + ni * 16 + li) * BK + (((ks * 4 + quad) ^ (li & 7)) * 8)];
      #pragma unroll
      for (int mi = 0; mi < MI; ++mi)
        #pragma unroll
        for (int ni = 0; ni < NI; ++ni)
          acc[mi][ni] = __builtin_amdgcn_mfma_f32_16x16x32_bf16(af[mi], bf[ni], acc[mi][ni], 0, 0, 0);
    }
    __syncthreads();
  }
  #pragma unroll
  for (int mi = 0; mi < MI; ++mi)
    #pragma unroll
    for (int ni = 0; ni < NI; ++ni) {
      int gcol = n0 + nbase + ni * 16 + li;
      float bv = bias[gcol];
      #pragma unroll
      for (int r = 0; r < 4; ++r) {
        int grow = m0 + mbase + mi * 16 + quad * 4 + r;
        Co[(size_t)grow * N + gcol] = acc[mi][ni][r] + bv;
      }
    }
}

// ---------- causal flash attention: R6-validated 16x16 version ----------
__global__ __launch_bounds__(256) void k_attn(
    const ushort* __restrict__ Q, const ushort* __restrict__ K,
    const ushort* __restrict__ Vt, ushort* __restrict__ O) {
  __shared__ ushort Kbuf[2][64 * 64];
  __shared__ ushort Vbuf[2][64 * 64];
  int lane = threadIdx.x & 63, wave = threadIdx.x >> 6;
  int quad = lane >> 4, li = lane & 15;
  int bh = blockIdx.x;                             // x = bh: XCD round-robin, K/V hot in L2
  int yi = (int)blockIdx.y;                        // balanced qt permutation
  int qb = (yi < 8) ? 31 - yi : (yi < 16) ? yi - 8 : (yi < 24) ? 39 - yi : yi - 16;
  int b = bh >> 4, hh = bh & 15;
  int q0 = qb * 64 + wave * 16;
  const ushort* Qb = Q  + (size_t)bh * S_ * HD_;
  const ushort* Kb = K  + (size_t)bh * S_ * HD_;
  const ushort* Vb = Vt + (size_t)bh * HD_ * S_;

  frag_t qf[2];  // B-operand: n = li (=q), k = quad*8+j
  #pragma unroll
  for (int ks = 0; ks < 2; ++ks)
    qf[ks] = *(const frag_t*)&Qb[(size_t)(q0 + li) * HD_ + ks * 32 + quad * 8];

  frag_t ones;                                     // bf16 1.0 splat (A for col-sum MFMA)
  #pragma unroll
  for (int i = 0; i < 8; ++i) ones[i] = (short)0x3F80;

  f32x4 o[4] = {};                                 // C[hd][q]: hd=ht*16+quad*4+r, q=li
  f32x4 lacc = {};                                 // P column sums (= per-q denom), row-bcast

  auto stage = [&](int kb, int bi) {
    #pragma unroll
    for (int i = 0; i < 2; ++i) {
      int rt  = wave * 16 + i * 8 + (lane >> 3);   // tile row
      int c16 = (lane & 7) ^ (lane >> 3);          // swizzle: (rt&7) == lane>>3
      gld_lds16(&Kb[(size_t)(kb * 64 + rt) * HD_ + c16 * 8], &Kbuf[bi][(wave * 16 + i * 8) * 64]);
      gld_lds16(&Vb[(size_t)rt * S_ + kb * 64 + c16 * 8],    &Vbuf[bi][(wave * 16 + i * 8) * 64]);
    }
  };

  auto comp = [&](int kb, bool diag, int bi) {
    f32x4 sc[4];                                   // sc[t][r] = S[key=t*16+quad*4+r][q=li]
    #pragma unroll
    for (int t = 0; t < 4; ++t) {
      f32x4 a = {};
      #pragma unroll
      for (int ks = 0; ks < 2; ++ks) {
        frag_t kf = *(const frag_t*)&Kbuf[bi][(t * 16 + li) * 64 + (((quad + ks * 4) ^ (li & 7)) * 8)];
        a = __builtin_amdgcn_mfma_f32_16x16x32_bf16(kf, qf[ks], a, 0, 0, 0);  // swapped QK^T
      }
      sc[t] = a;
    }
    if (diag) {
      #pragma unroll
      for (int t = 0; t < 4; ++t) {
        int key = kb * 64 + t * 16 + quad * 4;
        #pragma unroll
        for (int r = 0; r < 4; ++r)
          if (key + r > q0 + li) sc[t][r] = -1e30f;
      }
    }
    #pragma unroll
    for (int t = 0; t < 4; ++t)
      #pragma unroll
      for (int r = 0; r < 4; ++r)
        sc[t][r] = EXP2(sc[t][r]);                 // masked -> exp2(-1e30) = 0

    // in-register P -> B-operand frags (T12): per ks-half (32 keys = t-pair)
    frag_t pf[2];
    #pragma unroll
    for (int ks = 0; ks < 2; ++ks) {
      unsigned w0e, w1e, w0o, w1o;
      asm("v_cvt_pk_bf16_f32 %0, %1, %2" : "=v"(w0e) : "v"(sc[2*ks][0]),   "v"(sc[2*ks][1]));
      asm("v_cvt_pk_bf16_f32 %0, %1, %2" : "=v"(w1e) : "v"(sc[2*ks][2]),   "v"(sc[2*ks][3]));
      asm("v_cvt_pk_bf16_f32 %0, %1, %2" : "=v"(w0o) : "v"(sc[2*ks+1][0]), "v"(sc[2*ks+1][1]));
      asm("v_cvt_pk_bf16_f32 %0, %1, %2" : "=v"(w1o) : "v"(sc[2*ks+1][2]), "v"(sc[2*ks+1][3]));
      asm("v_permlane32_swap_b32 %0, %1" : "+v"(w0e), "+v"(w0o));
      asm("v_permlane32_swap_b32 %0, %1" : "+v"(w1e), "+v"(w1o));
      union { frag_t f; unsigned u[4]; } pu;
      pu.u[0] = w0e; pu.u[1] = w1e; pu.u[2] = w0o; pu.u[3] = w1o;
      pf[ks] = pu.f;
    }
    lacc = __builtin_amdgcn_mfma_f32_16x16x32_bf16(ones, pf[0], lacc, 0, 0, 0);
    lacc = __builtin_amdgcn_mfma_f32_16x16x32_bf16(ones, pf[1], lacc, 0, 0, 0);
    #pragma unroll
    for (int ht = 0; ht < 4; ++ht)
      #pragma unroll
      for (int ks = 0; ks < 2; ++ks) {             // V^T as A-operand (positions = kappa)
        frag_t vtf = *(const frag_t*)&Vbuf[bi][(ht * 16 + li) * 64 + (((ks * 4 + quad) ^ (li & 7)) * 8)];
        o[ht] = __builtin_amdgcn_mfma_f32_16x16x32_bf16(vtf, pf[ks], o[ht], 0, 0, 0);
      }
  };

  stage(0, 0);
  __syncthreads();                                 // DMA for kb=0 landed
  for (int kb = 0; kb <= qb; ++kb) {
    if (kb < qb) stage(kb + 1, (kb + 1) & 1);      // async DMA overlaps comp below
    comp(kb, kb == qb, kb & 1);
    __syncthreads();                               // drains DMA + guards buffer reuse
  }

  float inv = 1.f / lacc[0];                       // denom for q=li (row-broadcast)
  int srow = q0 + li;
  size_t obase = ((size_t)b * S_ + srow) * D_ + hh * 64 + quad * 4;
  #pragma unroll
  for (int ht = 0; ht < 4; ++ht) {                 // hd = ht*16+quad*4+r: 4 contiguous
    unsigned lo, hi;
    asm("v_cvt_pk_bf16_f32 %0, %1, %2" : "=v"(lo) : "v"(o[ht][0] * inv), "v"(o[ht][1] * inv));
    asm("v_cvt_pk_bf16_f32 %0, %1, %2" : "=v"(hi) : "v"(o[ht][2] * inv), "v"(o[ht][3] * inv));
    uint2 w; w.x = lo; w.y = hi;
    *(uint2*)&O[obase + ht * 16] = w;
  }
}

extern "C" void kernel_launch(void* const* d_in, const int* in_sizes, int n_in,
                              void* d_out, int out_size, void* d_ws, size_t ws_size,
                              hipStream_t stream) {
  (void)in_sizes; (void)n_in; (void)out_size; (void)ws_size;
  const float* x     = (const float*)d_in[0];
  const float* Wqkv  = (const float*)d_in[1];
  const float* bqkv  = (const float*)d_in[2];
  const float* Wproj = (const float*)d_in[3];
  const float* bproj = (const float*)d_in[4];
  float* out = (float*)d_out;

  char* ws = (char*)d_ws;                          // 40 MB used
  ushort* Xbf = (ushort*)(ws);                     //  8 MB  [4096,1024] bf16 (reused as O after attn)
  ushort* Wqt = (ushort*)(ws + (8u  << 20));       //  6 MB  [3072,1024] bf16
  ushort* Wpt = (ushort*)(ws + (14u << 20));       //  2 MB  [1024,1024] bf16
  ushort* Qbf = (ushort*)(ws + (16u << 20));       //  8 MB  [32,2048,64]  (pre-scaled by 0.125*log2e)
  ushort* Kbf = (ushort*)(ws + (24u << 20));       //  8 MB  [32,2048,64]
  ushort* Vtb = (ushort*)(ws + (32u << 20));       //  8 MB  [32,64,2048]  (V^T, sigma-permuted keys)
  ushort* Obf = Xbf;                               // X dead after QKV GEMM

  k_prep<<<dim3(2048), dim3(256), 0, stream>>>(x, Wqkv, Wproj, Xbf, Wqt, Wpt);
  k_gemm8<<<dim3(256), dim3(512), 0, stream>>>(Xbf, Wqt, bqkv, Qbf, Kbf, Vtb);
  k_attn<<<dim3(B_ * H_, 32), dim3(256), 0, stream>>>(Qbf, Kbf, Vtb, Obf);
  k_proj<<<dim3(8, 32), dim3(256), 0, stream>>>(Obf, Wpt, bproj, out);
}

// Round 9
// 165.786 us; speedup vs baseline: 1.0494x; 1.0494x over previous
//
#include <hip/hip_runtime.h>

using frag_t = __attribute__((ext_vector_type(8))) short;   // 8 x bf16 (4 VGPRs)
using f32x4  = __attribute__((ext_vector_type(4))) float;   // MFMA C/D

#define L2E 1.4426950408889634f

#if __has_builtin(__builtin_amdgcn_exp2f)
#define EXP2(x) __builtin_amdgcn_exp2f(x)   // raw v_exp_f32 (no denormal fixup seq)
#else
#define EXP2(x) exp2f(x)
#endif

constexpr int B_  = 2, S_ = 2048, D_ = 1024, H_ = 16, HD_ = 64;
constexpr float QSCALE = 0.125f * L2E;   // fold softmax log2e into Q

__device__ __forceinline__ ushort f2bf(float f) {
  union { float f; unsigned u; } v; v.f = f;
  unsigned u = v.u;
  unsigned r = (u + 0x7FFFu + ((u >> 16) & 1u)) >> 16;  // round-nearest-even
  return (ushort)r;
}

// async 16B/lane global->LDS (lds dest = wave-uniform base + lane*16) [m97]
__device__ __forceinline__ void gld_lds16(const ushort* g, ushort* l) {
  __builtin_amdgcn_global_load_lds((const __attribute__((address_space(1))) void*)g,
                                   (__attribute__((address_space(3))) void*)l, 16, 0, 0);
}

// ---------- fused prep: x->bf16  |  Wqkv^T->bf16  |  Wproj^T->bf16 ----------
__global__ __launch_bounds__(256) void k_prep(
    const float* __restrict__ x, const float* __restrict__ Wqkv,
    const float* __restrict__ Wproj,
    ushort* __restrict__ Xbf, ushort* __restrict__ Wqt, ushort* __restrict__ Wpt) {
  int blk = blockIdx.x, tid = threadIdx.x;
  if (blk < 1024) {                                 // x convert: 4096 elems/block
    size_t base = (size_t)blk * 4096 + tid * 4;
    #pragma unroll
    for (int i = 0; i < 4; ++i) {
      float4 f = *(const float4*)(x + base + i * 1024);
      ushort4 o;
      o.x = f2bf(f.x); o.y = f2bf(f.y); o.z = f2bf(f.z); o.w = f2bf(f.w);
      *(ushort4*)(Xbf + base + i * 1024) = o;
    }
  } else {                                          // W [K,N] -> W^T [N,K] bf16, 64x64 tile
    __shared__ float tile[64][65];
    const float* in; ushort* out; int N, K, bx, by;
    if (blk < 1024 + 768) { int b2 = blk - 1024; in = Wqkv;  out = Wqt; N = 3072; K = 1024; bx = b2 % 48; by = b2 / 48; }
    else                  { int b2 = blk - 1792; in = Wproj; out = Wpt; N = 1024; K = 1024; bx = b2 % 16; by = b2 / 16; }
    int n0 = bx * 64, k0 = by * 64;
    int tx = tid & 63, ty = tid >> 6;               // (64,4)
    #pragma unroll
    for (int i = 0; i < 16; ++i)
      tile[ty + i * 4][tx] = in[(size_t)(k0 + ty + i * 4) * N + n0 + tx];
    __syncthreads();
    #pragma unroll
    for (int i = 0; i < 16; ++i)
      out[(size_t)(n0 + ty + i * 4) * K + k0 + tx] = f2bf(tile[tx][ty + i * 4]);
  }
}

// ---------- 128x384 8-phase QKV GEMM (R6 geometry, sigma V^T — validated) ----------
__global__ __launch_bounds__(512, 2) void k_gemm8(
    const ushort* __restrict__ A, const ushort* __restrict__ Bt,
    const float* __restrict__ bias,
    ushort* __restrict__ Qo, ushort* __restrict__ Ko, ushort* __restrict__ Vo) {
  __shared__ ushort smem[65536];                    // 128 KiB
  int tid = threadIdx.x;
  int lane = tid & 63, wave = tid >> 6;
  int quad = lane >> 4, li = lane & 15;
  int wm = wave >> 1, wn = wave & 1;                // 4M x 2N
  int wg = blockIdx.x;                              // 256 = 8(N) x 32(M)
  int bx = wg & 7, by = wg >> 3;                    // bx == XCD: B-panel L2-resident
  int m0 = by * 128, n0 = bx * 384;
  const ushort* Asrc = A  + (size_t)m0 * 1024;
  const ushort* Bsrc = Bt + (size_t)n0 * 1024;
  int schunk = (tid & 3) ^ ((tid >> 4) & 3);        // stored pos -> source chunk
  int pos    = (quad ^ ((li >> 2) & 3)) * 8;        // frag read position (elems)

#define STGA(BI, KS, KT) \
    gld_lds16(&Asrc[(size_t)(tid >> 2) * 1024 + (KT)*64 + (KS)*32 + schunk*8], \
              &smem[(BI)*32768 + (KS)*4096 + wave*512])

#define STGB(BI, KS, KT) do { \
    _Pragma("unroll") \
    for (int p = 0; p < 3; ++p) \
      gld_lds16(&Bsrc[(size_t)(p*128 + (tid >> 2)) * 1024 + (KT)*64 + (KS)*32 + schunk*8], \
                &smem[(BI)*32768 + 8192 + (KS)*12288 + p*4096 + wave*512]); \
  } while (0)

  f32x4 acc[2][12] = {};
  frag_t af[2], bf[6];

#define PH(BI, KS, NH, STGS, W4) do { \
    if ((NH) == 0) { \
      _Pragma("unroll") \
      for (int mi = 0; mi < 2; ++mi) \
        af[mi] = *(const frag_t*)&smem[(BI)*32768 + (KS)*4096 + (wm*32 + mi*16 + li)*32 + pos]; \
    } \
    _Pragma("unroll") \
    for (int nj = 0; nj < 6; ++nj) \
      bf[nj] = *(const frag_t*)&smem[(BI)*32768 + 8192 + (KS)*12288 + (wn*192 + ((NH)*6 + nj)*16 + li)*32 + pos]; \
    STGS; \
    if (W4) asm volatile("s_waitcnt vmcnt(4)" ::: "memory"); \
    asm volatile("s_barrier" ::: "memory"); \
    __builtin_amdgcn_s_setprio(1); \
    _Pragma("unroll") \
    for (int mi = 0; mi < 2; ++mi) \
      _Pragma("unroll") \
      for (int nj = 0; nj < 6; ++nj) \
        acc[mi][(NH)*6 + nj] = __builtin_amdgcn_mfma_f32_16x16x32_bf16(af[mi], bf[nj], acc[mi][(NH)*6 + nj], 0, 0, 0); \
    __builtin_amdgcn_s_setprio(0); \
    asm volatile("s_barrier" ::: "memory"); \
  } while (0)

  STGA(0,0,0); STGB(0,0,0); STGA(0,1,0); STGB(0,1,0);
  STGA(1,0,1); STGB(1,0,1);
  asm volatile("s_waitcnt vmcnt(4)" ::: "memory");
  asm volatile("s_barrier" ::: "memory");

  for (int it = 0; it < 8; ++it) {                  // 2 K-tiles / iter, NT=16
    int t1 = 2*it + 1;
    int t2 = (2*it + 2 < 16) ? 2*it + 2 : 15;       // clamp: dead stage keeps
    int t3 = (2*it + 3 < 16) ? 2*it + 3 : 15;       //   vmcnt counts uniform
    PH(0,0,0, STGA(1,1,t1), 0);
    PH(0,0,1, STGB(1,1,t1), 0);
    PH(0,1,0, STGA(0,0,t2), 0);
    PH(0,1,1, STGB(0,0,t2), 1);
    PH(1,0,0, STGA(0,1,t2), 0);
    PH(1,0,1, STGB(0,1,t2), 0);
    PH(1,1,0, STGA(1,0,t3), 0);
    PH(1,1,1, STGB(1,0,t3), 1);
  }
#undef PH
#undef STGA
#undef STGB

  asm volatile("s_waitcnt vmcnt(0)" ::: "memory");  // drain dead stages before LDS reuse
  __syncthreads();

  // epilogue: C row = quad*4+r (M), col = li (N)  [m89/m91]
  #pragma unroll
  for (int nf = 0; nf < 12; ++nf) {
    int col0 = n0 + wn * 192 + nf * 16;             // 16-aligned, region-uniform
    int which = col0 >> 10;                         // 0=Q 1=K 2=V
    float bv = bias[col0 + li];
    if (which < 2) {                                // Q / K: [bh][s][hd]
      int d = (col0 + li) & 1023;
      int h = d >> 6, hd = d & 63;
      #pragma unroll
      for (int mi = 0; mi < 2; ++mi)
        #pragma unroll
        for (int r = 0; r < 4; ++r) {
          int grow = m0 + wm * 32 + mi * 16 + quad * 4 + r;
          int b = grow >> 11, s = grow & 2047;
          size_t off = (((size_t)b * H_ + h) * S_ + s) * HD_ + hd;
          float v = acc[mi][nf][r] + bv;
          if (which == 0) Qo[off] = f2bf(v * QSCALE);
          else            Ko[off] = f2bf(v);
        }
    } else {                                        // V -> sigma-permuted V^T (R6-validated)
      // natural key n = mi*16 + quad*4 + r (wave 32-span); position p = sigma(n):
      // within each 32-block, swap 4-groups 1<->2 of each 16 (involution),
      // matching attn's permlane32_swap frag basis.
      ushort* vl = &smem[wave * 640];               // [16 hd][40 pad] per wave
      int gq = (quad == 1 || quad == 2) ? (quad ^ 3) : quad;
      #pragma unroll
      for (int mi = 0; mi < 2; ++mi) {
        union { ushort u[4]; uint2 w; } pk;
        #pragma unroll
        for (int r = 0; r < 4; ++r) pk.u[r] = f2bf(acc[mi][nf][r] + bv);
        *(uint2*)&vl[li * 40 + mi * 16 + gq * 4] = pk.w;
      }
      int h = (col0 >> 6) & 15, hd0 = col0 & 63;
      int b = m0 >> 11, s0 = (m0 & 2047) + wm * 32;
      int rt = lane >> 2, kc = (lane & 3) * 8;      // 16 hd-rows x 4 key-chunks
      uint4 w = *(const uint4*)&vl[rt * 40 + kc];
      *(uint4*)&Vo[((size_t)(b * H_ + h) * HD_ + hd0 + rt) * S_ + s0 + kc] = w;
    }
  }
}

// ---------- proj GEMM: m97 structure, BM=128/BN=64 (R6-validated, 2 WG/CU) ----------
// R9: revert R8's 128x128 (1 WG/CU, -8us): inter-WG overlap [m114] beats
// per-WG MFMA:barrier density in this grid regime.
__global__ __launch_bounds__(256) void k_proj(
    const ushort* __restrict__ A, const ushort* __restrict__ Bt,
    const float* __restrict__ bias, float* __restrict__ Co) {
  constexpr int BM = 128, BN = 64, BK = 64, MI = 4, NI = 2;
  constexpr int N = 1024, K = 1024;
  __shared__ ushort smem[(BM + BN) * BK];
  ushort* As = smem;
  ushort* Bs = smem + BM * BK;
  int tid  = threadIdx.x;
  int lane = tid & 63, wave = tid >> 6;
  int quad = lane >> 4, li = lane & 15;
  int mbase = (wave >> 1) * (MI * 16);              // 2x2 waves
  int nbase = (wave & 1) * 32;
  int m0 = blockIdx.y * BM, n0 = blockIdx.x * BN;
  int srow = lane >> 3;                             // within a wave: 8 rows x 128B
  int scol = ((lane & 7) ^ srow) * 8;               // XOR-swizzled global chunk
  f32x4 acc[MI][NI] = {};
  for (int k0 = 0; k0 < K; k0 += BK) {
    #pragma unroll
    for (int i = 0; i < 4; ++i) {                   // A: 128 rows
      int rbase = i * 32 + wave * 8;
      gld_lds16(&A[(size_t)(m0 + rbase + srow) * K + k0 + scol], &As[rbase * BK]);
    }
    #pragma unroll
    for (int i = 0; i < 2; ++i) {                   // B: 64 rows
      int rbase = wave * 16 + i * 8;
      gld_lds16(&Bt[(size_t)(n0 + rbase + srow) * K + k0 + scol], &Bs[rbase * BK]);
    }
    __syncthreads();                                // drains vmcnt (compiler-emitted)
    #pragma unroll
    for (int ks = 0; ks < 2; ++ks) {
      frag_t af[MI], bf[NI];
      #pragma unroll
      for (int mi = 0; mi < MI; ++mi)
        af[mi] = *(const frag_t*)&As[(mbase + mi * 16 + li) * BK + (((ks * 4 + quad) ^ (li & 7)) * 8)];
      #pragma unroll
      for (int ni = 0; ni < NI; ++ni)
        bf[ni] = *(const frag_t*)&Bs[(nbase + ni * 16 + li) * BK + (((ks * 4 + quad) ^ (li & 7)) * 8)];
      #pragma unroll
      for (int mi = 0; mi < MI; ++mi)
        #pragma unroll
        for (int ni = 0; ni < NI; ++ni)
          acc[mi][ni] = __builtin_amdgcn_mfma_f32_16x16x32_bf16(af[mi], bf[ni], acc[mi][ni], 0, 0, 0);
    }
    __syncthreads();
  }
  #pragma unroll
  for (int mi = 0; mi < MI; ++mi)
    #pragma unroll
    for (int ni = 0; ni < NI; ++ni) {
      int gcol = n0 + nbase + ni * 16 + li;
      float bv = bias[gcol];
      #pragma unroll
      for (int r = 0; r < 4; ++r) {
        int grow = m0 + mbase + mi * 16 + quad * 4 + r;
        Co[(size_t)grow * N + gcol] = acc[mi][ni][r] + bv;
      }
    }
}

// ---------- causal flash attention: R6-validated 16x16 version ----------
__global__ __launch_bounds__(256) void k_attn(
    const ushort* __restrict__ Q, const ushort* __restrict__ K,
    const ushort* __restrict__ Vt, ushort* __restrict__ O) {
  __shared__ ushort Kbuf[2][64 * 64];
  __shared__ ushort Vbuf[2][64 * 64];
  int lane = threadIdx.x & 63, wave = threadIdx.x >> 6;
  int quad = lane >> 4, li = lane & 15;
  int bh = blockIdx.x;                             // x = bh: XCD round-robin, K/V hot in L2
  int yi = (int)blockIdx.y;                        // balanced qt permutation
  int qb = (yi < 8) ? 31 - yi : (yi < 16) ? yi - 8 : (yi < 24) ? 39 - yi : yi - 16;
  int b = bh >> 4, hh = bh & 15;
  int q0 = qb * 64 + wave * 16;
  const ushort* Qb = Q  + (size_t)bh * S_ * HD_;
  const ushort* Kb = K  + (size_t)bh * S_ * HD_;
  const ushort* Vb = Vt + (size_t)bh * HD_ * S_;

  frag_t qf[2];  // B-operand: n = li (=q), k = quad*8+j
  #pragma unroll
  for (int ks = 0; ks < 2; ++ks)
    qf[ks] = *(const frag_t*)&Qb[(size_t)(q0 + li) * HD_ + ks * 32 + quad * 8];

  frag_t ones;                                     // bf16 1.0 splat (A for col-sum MFMA)
  #pragma unroll
  for (int i = 0; i < 8; ++i) ones[i] = (short)0x3F80;

  f32x4 o[4] = {};                                 // C[hd][q]: hd=ht*16+quad*4+r, q=li
  f32x4 lacc = {};                                 // P column sums (= per-q denom), row-bcast

  auto stage = [&](int kb, int bi) {
    #pragma unroll
    for (int i = 0; i < 2; ++i) {
      int rt  = wave * 16 + i * 8 + (lane >> 3);   // tile row
      int c16 = (lane & 7) ^ (lane >> 3);          // swizzle: (rt&7) == lane>>3
      gld_lds16(&Kb[(size_t)(kb * 64 + rt) * HD_ + c16 * 8], &Kbuf[bi][(wave * 16 + i * 8) * 64]);
      gld_lds16(&Vb[(size_t)rt * S_ + kb * 64 + c16 * 8],    &Vbuf[bi][(wave * 16 + i * 8) * 64]);
    }
  };

  auto comp = [&](int kb, bool diag, int bi) {
    f32x4 sc[4];                                   // sc[t][r] = S[key=t*16+quad*4+r][q=li]
    #pragma unroll
    for (int t = 0; t < 4; ++t) {
      f32x4 a = {};
      #pragma unroll
      for (int ks = 0; ks < 2; ++ks) {
        frag_t kf = *(const frag_t*)&Kbuf[bi][(t * 16 + li) * 64 + (((quad + ks * 4) ^ (li & 7)) * 8)];
        a = __builtin_amdgcn_mfma_f32_16x16x32_bf16(kf, qf[ks], a, 0, 0, 0);  // swapped QK^T
      }
      sc[t] = a;
    }
    if (diag) {
      #pragma unroll
      for (int t = 0; t < 4; ++t) {
        int key = kb * 64 + t * 16 + quad * 4;
        #pragma unroll
        for (int r = 0; r < 4; ++r)
          if (key + r > q0 + li) sc[t][r] = -1e30f;
      }
    }
    #pragma unroll
    for (int t = 0; t < 4; ++t)
      #pragma unroll
      for (int r = 0; r < 4; ++r)
        sc[t][r] = EXP2(sc[t][r]);                 // masked -> exp2(-1e30) = 0

    // in-register P -> B-operand frags (T12): per ks-half (32 keys = t-pair)
    frag_t pf[2];
    #pragma unroll
    for (int ks = 0; ks < 2; ++ks) {
      unsigned w0e, w1e, w0o, w1o;
      asm("v_cvt_pk_bf16_f32 %0, %1, %2" : "=v"(w0e) : "v"(sc[2*ks][0]),   "v"(sc[2*ks][1]));
      asm("v_cvt_pk_bf16_f32 %0, %1, %2" : "=v"(w1e) : "v"(sc[2*ks][2]),   "v"(sc[2*ks][3]));
      asm("v_cvt_pk_bf16_f32 %0, %1, %2" : "=v"(w0o) : "v"(sc[2*ks+1][0]), "v"(sc[2*ks+1][1]));
      asm("v_cvt_pk_bf16_f32 %0, %1, %2" : "=v"(w1o) : "v"(sc[2*ks+1][2]), "v"(sc[2*ks+1][3]));
      asm("v_permlane32_swap_b32 %0, %1" : "+v"(w0e), "+v"(w0o));
      asm("v_permlane32_swap_b32 %0, %1" : "+v"(w1e), "+v"(w1o));
      union { frag_t f; unsigned u[4]; } pu;
      pu.u[0] = w0e; pu.u[1] = w1e; pu.u[2] = w0o; pu.u[3] = w1o;
      pf[ks] = pu.f;
    }
    lacc = __builtin_amdgcn_mfma_f32_16x16x32_bf16(ones, pf[0], lacc, 0, 0, 0);
    lacc = __builtin_amdgcn_mfma_f32_16x16x32_bf16(ones, pf[1], lacc, 0, 0, 0);
    #pragma unroll
    for (int ht = 0; ht < 4; ++ht)
      #pragma unroll
      for (int ks = 0; ks < 2; ++ks) {             // V^T as A-operand (positions = kappa)
        frag_t vtf = *(const frag_t*)&Vbuf[bi][(ht * 16 + li) * 64 + (((ks * 4 + quad) ^ (li & 7)) * 8)];
        o[ht] = __builtin_amdgcn_mfma_f32_16x16x32_bf16(vtf, pf[ks], o[ht], 0, 0, 0);
      }
  };

  stage(0, 0);
  __syncthreads();                                 // DMA for kb=0 landed
  for (int kb = 0; kb <= qb; ++kb) {
    if (kb < qb) stage(kb + 1, (kb + 1) & 1);      // async DMA overlaps comp below
    comp(kb, kb == qb, kb & 1);
    __syncthreads();                               // drains DMA + guards buffer reuse
  }

  float inv = 1.f / lacc[0];                       // denom for q=li (row-broadcast)
  int srow = q0 + li;
  size_t obase = ((size_t)b * S_ + srow) * D_ + hh * 64 + quad * 4;
  #pragma unroll
  for (int ht = 0; ht < 4; ++ht) {                 // hd = ht*16+quad*4+r: 4 contiguous
    unsigned lo, hi;
    asm("v_cvt_pk_bf16_f32 %0, %1, %2" : "=v"(lo) : "v"(o[ht][0] * inv), "v"(o[ht][1] * inv));
    asm("v_cvt_pk_bf16_f32 %0, %1, %2" : "=v"(hi) : "v"(o[ht][2] * inv), "v"(o[ht][3] * inv));
    uint2 w; w.x = lo; w.y = hi;
    *(uint2*)&O[obase + ht * 16] = w;
  }
}

extern "C" void kernel_launch(void* const* d_in, const int* in_sizes, int n_in,
                              void* d_out, int out_size, void* d_ws, size_t ws_size,
                              hipStream_t stream) {
  (void)in_sizes; (void)n_in; (void)out_size; (void)ws_size;
  const float* x     = (const float*)d_in[0];
  const float* Wqkv  = (const float*)d_in[1];
  const float* bqkv  = (const float*)d_in[2];
  const float* Wproj = (const float*)d_in[3];
  const float* bproj = (const float*)d_in[4];
  float* out = (float*)d_out;

  char* ws = (char*)d_ws;                          // 40 MB used
  ushort* Xbf = (ushort*)(ws);                     //  8 MB  [4096,1024] bf16 (reused as O after attn)
  ushort* Wqt = (ushort*)(ws + (8u  << 20));       //  6 MB  [3072,1024] bf16
  ushort* Wpt = (ushort*)(ws + (14u << 20));       //  2 MB  [1024,1024] bf16
  ushort* Qbf = (ushort*)(ws + (16u << 20));       //  8 MB  [32,2048,64]  (pre-scaled by 0.125*log2e)
  ushort* Kbf = (ushort*)(ws + (24u << 20));       //  8 MB  [32,2048,64]
  ushort* Vtb = (ushort*)(ws + (32u << 20));       //  8 MB  [32,64,2048]  (V^T, sigma-permuted keys)
  ushort* Obf = Xbf;                               // X dead after QKV GEMM

  k_prep<<<dim3(2048), dim3(256), 0, stream>>>(x, Wqkv, Wproj, Xbf, Wqt, Wpt);
  k_gemm8<<<dim3(256), dim3(512), 0, stream>>>(Xbf, Wqt, bqkv, Qbf, Kbf, Vtb);
  k_attn<<<dim3(B_ * H_, 32), dim3(256), 0, stream>>>(Qbf, Kbf, Vtb, Obf);
  k_proj<<<dim3(16, 32), dim3(256), 0, stream>>>(Obf, Wpt, bproj, out);
}